// Round 1
// baseline (546.068 us; speedup 1.0000x reference)
//
#include <hip/hip_runtime.h>
#include <hip/hip_bf16.h>
#include <math.h>

#define IN_DIM 128
#define OUT_DIM 128
#define HEADS 4
#define HEAD_DIM 32
#define NREL 3
#define NEG_SLOPE 0.2f

static __device__ __forceinline__ float leaky(float x){ return x > 0.f ? x : NEG_SLOPE*x; }
static __device__ __forceinline__ unsigned bf16rn(float x){
  unsigned b = __float_as_uint(x);
  b += 0x7FFF + ((b>>16)&1u);
  return b>>16;
}

// --- softmax over the 3 relation weights ---
__global__ void k_prep(const float* __restrict__ rw, float* __restrict__ smw){
  if (threadIdx.x==0){
    float m = fmaxf(rw[0], fmaxf(rw[1], rw[2]));
    float e0=__expf(rw[0]-m), e1=__expf(rw[1]-m), e2=__expf(rw[2]-m);
    float inv = 1.f/(e0+e1+e2);
    smw[0]=e0*inv; smw[1]=e1*inv; smw[2]=e2*inv;
  }
}

// --- h[r] = x @ W[r]; fused att_src/att_dst dots; h stored packed bf16 ---
__global__ __launch_bounds__(256) void k_gemm(
    const float* __restrict__ x, const float* __restrict__ W,
    const float* __restrict__ att_s, const float* __restrict__ att_d,
    unsigned* __restrict__ hq, float* __restrict__ as_, float* __restrict__ ad_, int N){
  __shared__ float Wl[IN_DIM*OUT_DIM];       // 64 KB
  __shared__ float xl[64][IN_DIM+4];         // padded stride 132 (16B-aligned, 2-way-bank free)
  const int r = blockIdx.y;
  const int row0 = blockIdx.x*64;
  const int t = threadIdx.x;

  const float4* Wg = (const float4*)(W + (size_t)r*IN_DIM*OUT_DIM);
  float4* Wl4 = (float4*)Wl;
  #pragma unroll
  for (int i=0;i<16;i++) Wl4[t + 256*i] = Wg[t + 256*i];

  for (int i=t; i<64*32; i+=256){            // 64 rows x 32 float4
    int rr = i>>5, c4 = i&31;
    int row = row0+rr;
    float4 v = (row < N) ? ((const float4*)x)[(size_t)row*32 + c4] : float4{0.f,0.f,0.f,0.f};
    *(float4*)&xl[rr][c4*4] = v;
  }
  __syncthreads();

  const int rl = t>>2;          // local row 0..63
  const int head = t&3;         // 4 col-chunks of 32 = heads
  const int c0 = head*32;
  float acc[32];
  #pragma unroll
  for (int j=0;j<32;j++) acc[j]=0.f;
  for (int k=0;k<IN_DIM;k++){
    float xv = xl[rl][k];
    const float4* wp = (const float4*)&Wl[k*OUT_DIM + c0];
    #pragma unroll
    for (int j=0;j<8;j++){
      float4 w4 = wp[j];
      acc[4*j+0] = fmaf(xv, w4.x, acc[4*j+0]);
      acc[4*j+1] = fmaf(xv, w4.y, acc[4*j+1]);
      acc[4*j+2] = fmaf(xv, w4.z, acc[4*j+2]);
      acc[4*j+3] = fmaf(xv, w4.w, acc[4*j+3]);
    }
  }
  int row = row0 + rl;
  if (row >= N) return;

  const float* asv = att_s + (size_t)(r*HEADS + head)*HEAD_DIM;
  const float* adv = att_d + (size_t)(r*HEADS + head)*HEAD_DIM;
  float sa=0.f, sd=0.f;
  #pragma unroll
  for (int j=0;j<32;j++){ sa = fmaf(acc[j], asv[j], sa); sd = fmaf(acc[j], adv[j], sd); }
  size_t nidx = (size_t)r*N + row;
  as_[nidx*4 + head] = sa;
  ad_[nidx*4 + head] = sd;

  unsigned up[16];
  #pragma unroll
  for (int j=0;j<16;j++) up[j] = bf16rn(acc[2*j]) | (bf16rn(acc[2*j+1])<<16);
  uint4* hp = (uint4*)(hq + nidx*64 + (size_t)head*16);
  #pragma unroll
  for (int j=0;j<4;j++) hp[j] = ((uint4*)up)[j];
}

// --- CSR build: count per (rel,dst) ---
__global__ void k_count(const int* __restrict__ et, const int* __restrict__ ei,
                        int* __restrict__ counts, int E, int N){
  int e = blockIdx.x*256 + threadIdx.x;
  if (e >= E) return;
  int ty = et[e];
  int d  = ei[E + e];
  atomicAdd(&counts[(size_t)ty*N + d], 1);
}

// --- 3-kernel exclusive scan over M = 3N elements ---
__global__ void k_scan1(const int* __restrict__ counts, int* __restrict__ offs,
                        int* __restrict__ aux, int M){
  __shared__ int s[256];
  int idx = blockIdx.x*256 + threadIdx.x;
  int v = (idx < M) ? counts[idx] : 0;
  s[threadIdx.x] = v; __syncthreads();
  int x = v;
  for (int off=1; off<256; off<<=1){
    int y = (threadIdx.x >= off) ? s[threadIdx.x-off] : 0;
    __syncthreads();
    x += y; s[threadIdx.x] = x;
    __syncthreads();
  }
  if (idx < M) offs[idx] = x - v;
  if (threadIdx.x == 255) aux[blockIdx.x] = x;
}
__global__ void k_scan2(int* __restrict__ aux, int* __restrict__ offs, int M, int NB){
  __shared__ int s[1024];
  int t = threadIdx.x;
  int v = (t < NB) ? aux[t] : 0;
  s[t] = v; __syncthreads();
  int x = v;
  for (int off=1; off<1024; off<<=1){
    int y = (t >= off) ? s[t-off] : 0;
    __syncthreads();
    x += y; s[t] = x;
    __syncthreads();
  }
  if (t < NB) aux[t] = x - v;
  if (t == NB-1) offs[M] = x;   // grand total
}
__global__ void k_scan3(int* __restrict__ offs, const int* __restrict__ aux, int M){
  int idx = blockIdx.x*256 + threadIdx.x;
  if (idx < M) offs[idx] += aux[idx>>8];
}

// --- scatter edges into CSR order; precompute per-edge 4-head scores ---
__global__ void k_scatter(const int* __restrict__ et, const int* __restrict__ ei,
                          int* __restrict__ cursor, const float* __restrict__ as_,
                          const float* __restrict__ ad_, int* __restrict__ ssrc,
                          float4* __restrict__ sscore, int E, int N){
  int e = blockIdx.x*256 + threadIdx.x;
  if (e >= E) return;
  int ty = et[e];
  int s  = ei[e];
  int d  = ei[E+e];
  int pos = atomicAdd(&cursor[(size_t)ty*N + d], 1);
  ssrc[pos] = s;
  float4 a = ((const float4*)as_)[(size_t)ty*N + s];
  float4 b = ((const float4*)ad_)[(size_t)ty*N + d];
  float4 sc;
  sc.x = leaky(a.x+b.x); sc.y = leaky(a.y+b.y);
  sc.z = leaky(a.z+b.z); sc.w = leaky(a.w+b.w);
  sscore[e < 0 ? 0 : pos] = sc;
}

// --- per-dst softmax + aggregation, one wave per dst, all 3 relations ---
__global__ __launch_bounds__(256) void k_segment(
    const int* __restrict__ offs, const int* __restrict__ ssrc,
    const float4* __restrict__ sscore, const unsigned* __restrict__ hq,
    const float* __restrict__ as_, const float* __restrict__ ad_,
    const float* __restrict__ bias, const float* __restrict__ smw,
    float* __restrict__ out, int N){
  const int wave = threadIdx.x >> 6;
  const int lane = threadIdx.x & 63;
  const int dst  = blockIdx.x*4 + wave;
  if (dst >= N) return;
  const int head = lane >> 4;          // channel pair c0=2*lane -> head = c0/32

  float2 accT = {0.f, 0.f};
  for (int r=0; r<NREL; r++){
    const size_t seg = (size_t)r*N + dst;
    int beg = offs[seg], end = offs[seg+1];
    beg = __builtin_amdgcn_readfirstlane(beg);
    end = __builtin_amdgcn_readfirstlane(end);

    float4 a = ((const float4*)as_)[seg];
    float4 b = ((const float4*)ad_)[seg];
    float4 ssv;
    ssv.x = leaky(a.x+b.x); ssv.y = leaky(a.y+b.y);
    ssv.z = leaky(a.z+b.z); ssv.w = leaky(a.w+b.w);

    // pass 1: per-head max (self-loop included via init)
    float4 m = ssv;
    for (int i=beg+lane; i<end; i+=64){
      float4 sc = sscore[i];
      m.x=fmaxf(m.x,sc.x); m.y=fmaxf(m.y,sc.y);
      m.z=fmaxf(m.z,sc.z); m.w=fmaxf(m.w,sc.w);
    }
    #pragma unroll
    for (int o=32;o>0;o>>=1){
      m.x=fmaxf(m.x,__shfl_xor(m.x,o)); m.y=fmaxf(m.y,__shfl_xor(m.y,o));
      m.z=fmaxf(m.z,__shfl_xor(m.z,o)); m.w=fmaxf(m.w,__shfl_xor(m.w,o));
    }
    // pass 2: per-head denom
    float4 den = {0.f,0.f,0.f,0.f};
    for (int i=beg+lane; i<end; i+=64){
      float4 sc = sscore[i];
      den.x += __expf(sc.x-m.x); den.y += __expf(sc.y-m.y);
      den.z += __expf(sc.z-m.z); den.w += __expf(sc.w-m.w);
    }
    #pragma unroll
    for (int o=32;o>0;o>>=1){
      den.x+=__shfl_xor(den.x,o); den.y+=__shfl_xor(den.y,o);
      den.z+=__shfl_xor(den.z,o); den.w+=__shfl_xor(den.w,o);
    }
    den.x += __expf(ssv.x-m.x); den.y += __expf(ssv.y-m.y);
    den.z += __expf(ssv.z-m.z); den.w += __expf(ssv.w-m.w);

    float mh   = (head<2) ? (head==0?m.x:m.y)   : (head==2?m.z:m.w);
    float dh   = (head<2) ? (head==0?den.x:den.y) : (head==2?den.z:den.w);
    float sshv = (head<2) ? (head==0?ssv.x:ssv.y) : (head==2?ssv.z:ssv.w);
    float invd = 1.f/dh;

    // pass 3: serial over edges, 2 channels per lane
    float2 acc = {0.f, 0.f};
    const unsigned* hb = hq + (size_t)r*N*64;
    for (int i=beg; i<end; i++){
      int s = ssrc[i];
      s = __builtin_amdgcn_readfirstlane(s);
      float4 sc = sscore[i];
      float sch = (head<2) ? (head==0?sc.x:sc.y) : (head==2?sc.z:sc.w);
      float alpha = __expf(sch - mh)*invd;
      unsigned u = hb[(size_t)s*64 + lane];
      acc.x = fmaf(alpha, __uint_as_float(u<<16),         acc.x);
      acc.y = fmaf(alpha, __uint_as_float(u & 0xFFFF0000u), acc.y);
    }
    { // self-loop message
      float alpha = __expf(sshv - mh)*invd;
      unsigned u = hb[(size_t)dst*64 + lane];
      acc.x = fmaf(alpha, __uint_as_float(u<<16),         acc.x);
      acc.y = fmaf(alpha, __uint_as_float(u & 0xFFFF0000u), acc.y);
    }
    float w = smw[r];
    float2 bv = ((const float2*)(bias + (size_t)r*OUT_DIM))[lane];
    accT.x += w*(acc.x + bv.x);
    accT.y += w*(acc.y + bv.y);
  }
  ((float2*)out)[(size_t)dst*64 + lane] = accT;
}

extern "C" void kernel_launch(void* const* d_in, const int* in_sizes, int n_in,
                              void* d_out, int out_size, void* d_ws, size_t ws_size,
                              hipStream_t stream) {
  const float* x     = (const float*)d_in[0];
  const float* W     = (const float*)d_in[1];
  const float* att_s = (const float*)d_in[2];
  const float* att_d = (const float*)d_in[3];
  const float* bias  = (const float*)d_in[4];
  const float* rw    = (const float*)d_in[5];
  const int*   ei    = (const int*)d_in[6];
  const int*   et    = (const int*)d_in[7];
  float* out = (float*)d_out;

  const int N = in_sizes[0] / IN_DIM;
  const int E = in_sizes[7];
  const int M = NREL * N;

  char* ws = (char*)d_ws;
  size_t off = 0;
  auto alloc = [&](size_t bytes) -> void* {
    void* p = ws + off; off += (bytes + 255) & ~(size_t)255; return p;
  };
  unsigned* hq     = (unsigned*)alloc((size_t)M * 64 * 4);   // bf16-packed h [3][N][64]
  float*    as_    = (float*)   alloc((size_t)M * 4 * 4);
  float*    ad_    = (float*)   alloc((size_t)M * 4 * 4);
  int*      counts = (int*)     alloc((size_t)M * 4);
  int*      offs   = (int*)     alloc(((size_t)M + 1) * 4);
  int*      cursor = (int*)     alloc((size_t)M * 4);
  int*      aux    = (int*)     alloc(4096);
  int*      ssrc   = (int*)     alloc((size_t)E * 4);
  float4*   sscore = (float4*)  alloc((size_t)E * 16);
  float*    smw    = (float*)   alloc(256);

  hipMemsetAsync(counts, 0, (size_t)M * 4, stream);
  k_prep<<<1, 64, 0, stream>>>(rw, smw);
  dim3 g1((N + 63) / 64, NREL);
  k_gemm<<<g1, 256, 0, stream>>>(x, W, att_s, att_d, hq, as_, ad_, N);
  k_count<<<(E + 255) / 256, 256, 0, stream>>>(et, ei, counts, E, N);
  const int NB = (M + 255) / 256;
  k_scan1<<<NB, 256, 0, stream>>>(counts, offs, aux, M);
  k_scan2<<<1, 1024, 0, stream>>>(aux, offs, M, NB);
  k_scan3<<<NB, 256, 0, stream>>>(offs, aux, M);
  hipMemcpyAsync(cursor, offs, (size_t)M * 4, hipMemcpyDeviceToDevice, stream);
  k_scatter<<<(E + 255) / 256, 256, 0, stream>>>(et, ei, cursor, as_, ad_, ssrc, sscore, E, N);
  k_segment<<<(N + 3) / 4, 256, 0, stream>>>(offs, ssrc, sscore, hq, as_, ad_, bias, smw, out, N);
}

// Round 2
// 403.370 us; speedup vs baseline: 1.3538x; 1.3538x over previous
//
#include <hip/hip_runtime.h>
#include <hip/hip_bf16.h>
#include <math.h>

#define IN_DIM 128
#define OUT_DIM 128
#define HEADS 4
#define HEAD_DIM 32
#define NREL 3
#define NEG_SLOPE 0.2f

typedef __attribute__((ext_vector_type(8))) short short8;
typedef __attribute__((ext_vector_type(4))) float f32x4;
typedef unsigned short u16;

static __device__ __forceinline__ float leaky(float x){ return x > 0.f ? x : NEG_SLOPE*x; }
static __device__ __forceinline__ unsigned bf16rn(float x){
  unsigned b = __float_as_uint(x);
  b += 0x7FFF + ((b>>16)&1u);
  return b>>16;
}

// --- softmax over the 3 relation weights ---
__global__ void k_prep(const float* __restrict__ rw, float* __restrict__ smw){
  if (threadIdx.x==0){
    float m = fmaxf(rw[0], fmaxf(rw[1], rw[2]));
    float e0=__expf(rw[0]-m), e1=__expf(rw[1]-m), e2=__expf(rw[2]-m);
    float inv = 1.f/(e0+e1+e2);
    smw[0]=e0*inv; smw[1]=e1*inv; smw[2]=e2*inv;
  }
}

// --- build WTall[r][144][128] bf16: cols 0..127 = W^T, 128..135 = (W@att_mat)^T, 136..143 = 0 ---
__global__ void k_wprep(const float* __restrict__ W, const float* __restrict__ att_s,
                        const float* __restrict__ att_d, u16* __restrict__ WTall){
  const int r = blockIdx.x;
  const int t = threadIdx.x;
  const float* Wr = W + (size_t)r*IN_DIM*OUT_DIM;
  u16* WT = WTall + (size_t)r*144*128;
  for (int i=t; i<128*128; i+=256){
    int k = i>>7, col = i&127;
    WT[col*128 + k] = (u16)bf16rn(Wr[i]);          // Wr[i]=W[k][col]
  }
  if (t < 128){
    int k = t;
    for (int h=0; h<4; h++){
      float ss=0.f, sd=0.f;
      for (int c=0; c<32; c++){
        float w = Wr[k*128 + h*32 + c];
        ss = fmaf(w, att_s[(r*4+h)*32+c], ss);
        sd = fmaf(w, att_d[(r*4+h)*32+c], sd);
      }
      WT[(128+h)*128 + k] = (u16)bf16rn(ss);
      WT[(132+h)*128 + k] = (u16)bf16rn(sd);
    }
  }
  for (int i=t; i<8*128; i+=256) WT[136*128 + i] = 0;
}

// --- MFMA GEMM: h = x@W (bf16 in, fp32 acc) + fused a_s/a_d via extra B columns ---
// Block: 256 thr = 4 waves; each wave does 32 rows x 144 cols. No LDS, no barriers.
__global__ __launch_bounds__(256) void k_gemm(
    const float* __restrict__ x, const u16* __restrict__ WTall,
    unsigned* __restrict__ hq, float* __restrict__ as_, float* __restrict__ ad_, int N){
  const int r = blockIdx.y;
  const int w = threadIdx.x >> 6;
  const int l = threadIdx.x & 63;
  const int row0 = blockIdx.x*128 + w*32;
  const int lg = l >> 4;        // k-group / D-row group
  const int lc = l & 15;        // A-row / B-col / D-col

  const u16* WT = WTall + (size_t)r*144*128;

  f32x4 acc[2][9];
  #pragma unroll
  for (int rf=0; rf<2; rf++)
    #pragma unroll
    for (int cf=0; cf<9; cf++) acc[rf][cf] = (f32x4){0.f,0.f,0.f,0.f};

  for (int ks=0; ks<4; ks++){
    const int k0 = ks*32 + lg*8;
    short8 a[2];
    #pragma unroll
    for (int rf=0; rf<2; rf++){
      int row = row0 + rf*16 + lc;
      float4 v0, v1;
      if (row < N){
        const float4* xp = (const float4*)(x + (size_t)row*IN_DIM + k0);
        v0 = xp[0]; v1 = xp[1];
      } else { v0 = float4{0.f,0.f,0.f,0.f}; v1 = v0; }
      union { short8 s; unsigned u[4]; } pa;
      pa.u[0] = bf16rn(v0.x) | (bf16rn(v0.y)<<16);
      pa.u[1] = bf16rn(v0.z) | (bf16rn(v0.w)<<16);
      pa.u[2] = bf16rn(v1.x) | (bf16rn(v1.y)<<16);
      pa.u[3] = bf16rn(v1.z) | (bf16rn(v1.w)<<16);
      a[rf] = pa.s;
    }
    #pragma unroll
    for (int cf=0; cf<9; cf++){
      union { short8 s; uint4 u; } pb;
      pb.u = *(const uint4*)(WT + (size_t)(cf*16 + lc)*128 + k0);
      #pragma unroll
      for (int rf=0; rf<2; rf++)
        acc[rf][cf] = __builtin_amdgcn_mfma_f32_16x16x32_bf16(a[rf], pb.s, acc[rf][cf], 0, 0, 0);
    }
  }

  // epilogue: D[row=(lg*4+j)][col=cf*16+lc]
  #pragma unroll
  for (int rf=0; rf<2; rf++){
    #pragma unroll
    for (int j=0; j<4; j++){
      int row = row0 + rf*16 + lg*4 + j;
      bool ok = (row < N);
      size_t nidx = (size_t)r*N + row;
      #pragma unroll
      for (int cf=0; cf<8; cf++){
        float v = acc[rf][cf][j];
        float pv = __shfl_xor(v, 1);        // partner holds odd col
        if (ok && !(l&1))
          hq[nidx*64 + cf*8 + (lc>>1)] = bf16rn(v) | (bf16rn(pv)<<16);
      }
      float av = acc[rf][8][j];
      if (ok && lc < 4)       as_[nidx*4 + lc]     = av;
      else if (ok && lc < 8)  ad_[nidx*4 + (lc-4)] = av;
    }
  }
}

// --- CSR build: count per (rel,dst) ---
__global__ void k_count(const int* __restrict__ et, const int* __restrict__ ei,
                        int* __restrict__ counts, int E, int N){
  int e = blockIdx.x*256 + threadIdx.x;
  if (e >= E) return;
  int ty = et[e];
  int d  = ei[E + e];
  atomicAdd(&counts[(size_t)ty*N + d], 1);
}

// --- 3-kernel exclusive scan over M = 3N elements ---
__global__ void k_scan1(const int* __restrict__ counts, int* __restrict__ offs,
                        int* __restrict__ aux, int M){
  __shared__ int s[256];
  int idx = blockIdx.x*256 + threadIdx.x;
  int v = (idx < M) ? counts[idx] : 0;
  s[threadIdx.x] = v; __syncthreads();
  int x = v;
  for (int off=1; off<256; off<<=1){
    int y = (threadIdx.x >= off) ? s[threadIdx.x-off] : 0;
    __syncthreads();
    x += y; s[threadIdx.x] = x;
    __syncthreads();
  }
  if (idx < M) offs[idx] = x - v;
  if (threadIdx.x == 255) aux[blockIdx.x] = x;
}
__global__ void k_scan2(int* __restrict__ aux, int* __restrict__ offs, int M, int NB){
  __shared__ int s[1024];
  int t = threadIdx.x;
  int v = (t < NB) ? aux[t] : 0;
  s[t] = v; __syncthreads();
  int x = v;
  for (int off=1; off<1024; off<<=1){
    int y = (t >= off) ? s[t-off] : 0;
    __syncthreads();
    x += y; s[t] = x;
    __syncthreads();
  }
  if (t < NB) aux[t] = x - v;
  if (t == NB-1) offs[M] = x;
}
__global__ void k_scan3(int* __restrict__ offs, const int* __restrict__ aux, int M){
  int idx = blockIdx.x*256 + threadIdx.x;
  if (idx < M) offs[idx] += aux[idx>>8];
}

// --- scatter edges into CSR order; precompute per-edge 4-head scores ---
__global__ void k_scatter(const int* __restrict__ et, const int* __restrict__ ei,
                          int* __restrict__ cursor, const float* __restrict__ as_,
                          const float* __restrict__ ad_, int* __restrict__ ssrc,
                          float4* __restrict__ sscore, int E, int N){
  int e = blockIdx.x*256 + threadIdx.x;
  if (e >= E) return;
  int ty = et[e];
  int s  = ei[e];
  int d  = ei[E+e];
  int pos = atomicAdd(&cursor[(size_t)ty*N + d], 1);
  ssrc[pos] = s;
  float4 a = ((const float4*)as_)[(size_t)ty*N + s];
  float4 b = ((const float4*)ad_)[(size_t)ty*N + d];
  float4 sc;
  sc.x = leaky(a.x+b.x); sc.y = leaky(a.y+b.y);
  sc.z = leaky(a.z+b.z); sc.w = leaky(a.w+b.w);
  sscore[pos] = sc;
}

// --- per-dst softmax + aggregation, one wave per dst, all 3 relations ---
__global__ __launch_bounds__(256) void k_segment(
    const int* __restrict__ offs, const int* __restrict__ ssrc,
    const float4* __restrict__ sscore, const unsigned* __restrict__ hq,
    const float* __restrict__ as_, const float* __restrict__ ad_,
    const float* __restrict__ bias, const float* __restrict__ smw,
    float* __restrict__ out, int N){
  const int wave = threadIdx.x >> 6;
  const int lane = threadIdx.x & 63;
  const int dst  = blockIdx.x*4 + wave;
  if (dst >= N) return;
  const int head = lane >> 4;

  float2 accT = {0.f, 0.f};
  for (int r=0; r<NREL; r++){
    const size_t seg = (size_t)r*N + dst;
    int beg = offs[seg], end = offs[seg+1];
    beg = __builtin_amdgcn_readfirstlane(beg);
    end = __builtin_amdgcn_readfirstlane(end);

    float4 a = ((const float4*)as_)[seg];
    float4 b = ((const float4*)ad_)[seg];
    float4 ssv;
    ssv.x = leaky(a.x+b.x); ssv.y = leaky(a.y+b.y);
    ssv.z = leaky(a.z+b.z); ssv.w = leaky(a.w+b.w);

    float4 m = ssv;
    for (int i=beg+lane; i<end; i+=64){
      float4 sc = sscore[i];
      m.x=fmaxf(m.x,sc.x); m.y=fmaxf(m.y,sc.y);
      m.z=fmaxf(m.z,sc.z); m.w=fmaxf(m.w,sc.w);
    }
    #pragma unroll
    for (int o=32;o>0;o>>=1){
      m.x=fmaxf(m.x,__shfl_xor(m.x,o)); m.y=fmaxf(m.y,__shfl_xor(m.y,o));
      m.z=fmaxf(m.z,__shfl_xor(m.z,o)); m.w=fmaxf(m.w,__shfl_xor(m.w,o));
    }
    float4 den = {0.f,0.f,0.f,0.f};
    for (int i=beg+lane; i<end; i+=64){
      float4 sc = sscore[i];
      den.x += __expf(sc.x-m.x); den.y += __expf(sc.y-m.y);
      den.z += __expf(sc.z-m.z); den.w += __expf(sc.w-m.w);
    }
    #pragma unroll
    for (int o=32;o>0;o>>=1){
      den.x+=__shfl_xor(den.x,o); den.y+=__shfl_xor(den.y,o);
      den.z+=__shfl_xor(den.z,o); den.w+=__shfl_xor(den.w,o);
    }
    den.x += __expf(ssv.x-m.x); den.y += __expf(ssv.y-m.y);
    den.z += __expf(ssv.z-m.z); den.w += __expf(ssv.w-m.w);

    float mh   = (head<2) ? (head==0?m.x:m.y)   : (head==2?m.z:m.w);
    float dh   = (head<2) ? (head==0?den.x:den.y) : (head==2?den.z:den.w);
    float sshv = (head<2) ? (head==0?ssv.x:ssv.y) : (head==2?ssv.z:ssv.w);
    float invd = 1.f/dh;

    float2 acc = {0.f, 0.f};
    const unsigned* hb = hq + (size_t)r*N*64;
    for (int i=beg; i<end; i++){
      int s = ssrc[i];
      s = __builtin_amdgcn_readfirstlane(s);
      float4 sc = sscore[i];
      float sch = (head<2) ? (head==0?sc.x:sc.y) : (head==2?sc.z:sc.w);
      float alpha = __expf(sch - mh)*invd;
      unsigned u = hb[(size_t)s*64 + lane];
      acc.x = fmaf(alpha, __uint_as_float(u<<16),           acc.x);
      acc.y = fmaf(alpha, __uint_as_float(u & 0xFFFF0000u), acc.y);
    }
    {
      float alpha = __expf(sshv - mh)*invd;
      unsigned u = hb[(size_t)dst*64 + lane];
      acc.x = fmaf(alpha, __uint_as_float(u<<16),           acc.x);
      acc.y = fmaf(alpha, __uint_as_float(u & 0xFFFF0000u), acc.y);
    }
    float w = smw[r];
    float2 bv = ((const float2*)(bias + (size_t)r*OUT_DIM))[lane];
    accT.x += w*(acc.x + bv.x);
    accT.y += w*(acc.y + bv.y);
  }
  ((float2*)out)[(size_t)dst*64 + lane] = accT;
}

extern "C" void kernel_launch(void* const* d_in, const int* in_sizes, int n_in,
                              void* d_out, int out_size, void* d_ws, size_t ws_size,
                              hipStream_t stream) {
  const float* x     = (const float*)d_in[0];
  const float* W     = (const float*)d_in[1];
  const float* att_s = (const float*)d_in[2];
  const float* att_d = (const float*)d_in[3];
  const float* bias  = (const float*)d_in[4];
  const float* rw    = (const float*)d_in[5];
  const int*   ei    = (const int*)d_in[6];
  const int*   et    = (const int*)d_in[7];
  float* out = (float*)d_out;

  const int N = in_sizes[0] / IN_DIM;
  const int E = in_sizes[7];
  const int M = NREL * N;

  char* ws = (char*)d_ws;
  size_t off = 0;
  auto alloc = [&](size_t bytes) -> void* {
    void* p = ws + off; off += (bytes + 255) & ~(size_t)255; return p;
  };
  unsigned* hq     = (unsigned*)alloc((size_t)M * 64 * 4);   // bf16-packed h [3][N][64]
  float*    as_    = (float*)   alloc((size_t)M * 4 * 4);
  float*    ad_    = (float*)   alloc((size_t)M * 4 * 4);
  int*      counts = (int*)     alloc((size_t)M * 4);
  int*      offs   = (int*)     alloc(((size_t)M + 1) * 4);
  int*      cursor = (int*)     alloc((size_t)M * 4);
  int*      aux    = (int*)     alloc(4096);
  int*      ssrc   = (int*)     alloc((size_t)E * 4);
  float4*   sscore = (float4*)  alloc((size_t)E * 16);
  float*    smw    = (float*)   alloc(256);
  u16*      WTall  = (u16*)     alloc((size_t)NREL * 144 * 128 * 2);

  hipMemsetAsync(counts, 0, (size_t)M * 4, stream);
  k_prep<<<1, 64, 0, stream>>>(rw, smw);
  k_wprep<<<NREL, 256, 0, stream>>>(W, att_s, att_d, WTall);
  dim3 g1((N + 127) / 128, NREL);
  k_gemm<<<g1, 256, 0, stream>>>(x, WTall, hq, as_, ad_, N);
  k_count<<<(E + 255) / 256, 256, 0, stream>>>(et, ei, counts, E, N);
  const int NB = (M + 255) / 256;
  k_scan1<<<NB, 256, 0, stream>>>(counts, offs, aux, M);
  k_scan2<<<1, 1024, 0, stream>>>(aux, offs, M, NB);
  k_scan3<<<NB, 256, 0, stream>>>(offs, aux, M);
  hipMemcpyAsync(cursor, offs, (size_t)M * 4, hipMemcpyDeviceToDevice, stream);
  k_scatter<<<(E + 255) / 256, 256, 0, stream>>>(et, ei, cursor, as_, ad_, ssrc, sscore, E, N);
  k_segment<<<(N + 3) / 4, 256, 0, stream>>>(offs, ssrc, sscore, hq, as_, ad_, bias, smw, out, N);
}

// Round 3
// 351.446 us; speedup vs baseline: 1.5538x; 1.1477x over previous
//
#include <hip/hip_runtime.h>
#include <hip/hip_bf16.h>
#include <math.h>

#define IN_DIM 128
#define OUT_DIM 128
#define HEADS 4
#define HEAD_DIM 32
#define NREL 3
#define NEG_SLOPE 0.2f

typedef __attribute__((ext_vector_type(8))) short short8;
typedef __attribute__((ext_vector_type(4))) float f32x4;
typedef unsigned short u16;

static __device__ __forceinline__ float leaky(float x){ return x > 0.f ? x : NEG_SLOPE*x; }
static __device__ __forceinline__ unsigned bf16rn(float x){
  unsigned b = __float_as_uint(x);
  b += 0x7FFF + ((b>>16)&1u);
  return b>>16;
}

// --- softmax over the 3 relation weights ---
__global__ void k_prep(const float* __restrict__ rw, float* __restrict__ smw){
  if (threadIdx.x==0){
    float m = fmaxf(rw[0], fmaxf(rw[1], rw[2]));
    float e0=__expf(rw[0]-m), e1=__expf(rw[1]-m), e2=__expf(rw[2]-m);
    float inv = 1.f/(e0+e1+e2);
    smw[0]=e0*inv; smw[1]=e1*inv; smw[2]=e2*inv;
  }
}

// --- build WTall[r][144][128] bf16: cols 0..127 = W^T, 128..135 = (W@att)^T, 136..143 = 0 ---
__global__ void k_wprep(const float* __restrict__ W, const float* __restrict__ att_s,
                        const float* __restrict__ att_d, u16* __restrict__ WTall){
  const int r = blockIdx.x;
  const int t = threadIdx.x;
  const float* Wr = W + (size_t)r*IN_DIM*OUT_DIM;
  u16* WT = WTall + (size_t)r*144*128;
  for (int i=t; i<128*128; i+=256){
    int k = i>>7, col = i&127;
    WT[col*128 + k] = (u16)bf16rn(Wr[i]);
  }
  if (t < 128){
    int k = t;
    for (int h=0; h<4; h++){
      float ss=0.f, sd=0.f;
      for (int c=0; c<32; c++){
        float w = Wr[k*128 + h*32 + c];
        ss = fmaf(w, att_s[(r*4+h)*32+c], ss);
        sd = fmaf(w, att_d[(r*4+h)*32+c], sd);
      }
      WT[(128+h)*128 + k] = (u16)bf16rn(ss);
      WT[(132+h)*128 + k] = (u16)bf16rn(sd);
    }
  }
  for (int i=t; i<8*128; i+=256) WT[136*128 + i] = 0;
}

// --- MFMA GEMM: h = x@W (bf16 in, fp32 acc) + fused a_s/a_d via extra B columns ---
__global__ __launch_bounds__(256) void k_gemm(
    const float* __restrict__ x, const u16* __restrict__ WTall,
    unsigned* __restrict__ hq, float* __restrict__ as_, float* __restrict__ ad_, int N){
  const int r = blockIdx.y;
  const int w = threadIdx.x >> 6;
  const int l = threadIdx.x & 63;
  const int row0 = blockIdx.x*128 + w*32;
  const int lg = l >> 4;
  const int lc = l & 15;

  const u16* WT = WTall + (size_t)r*144*128;

  f32x4 acc[2][9];
  #pragma unroll
  for (int rf=0; rf<2; rf++)
    #pragma unroll
    for (int cf=0; cf<9; cf++) acc[rf][cf] = (f32x4){0.f,0.f,0.f,0.f};

  for (int ks=0; ks<4; ks++){
    const int k0 = ks*32 + lg*8;
    short8 a[2];
    #pragma unroll
    for (int rf=0; rf<2; rf++){
      int row = row0 + rf*16 + lc;
      float4 v0, v1;
      if (row < N){
        const float4* xp = (const float4*)(x + (size_t)row*IN_DIM + k0);
        v0 = xp[0]; v1 = xp[1];
      } else { v0 = float4{0.f,0.f,0.f,0.f}; v1 = v0; }
      union { short8 s; unsigned u[4]; } pa;
      pa.u[0] = bf16rn(v0.x) | (bf16rn(v0.y)<<16);
      pa.u[1] = bf16rn(v0.z) | (bf16rn(v0.w)<<16);
      pa.u[2] = bf16rn(v1.x) | (bf16rn(v1.y)<<16);
      pa.u[3] = bf16rn(v1.z) | (bf16rn(v1.w)<<16);
      a[rf] = pa.s;
    }
    #pragma unroll
    for (int cf=0; cf<9; cf++){
      union { short8 s; uint4 u; } pb;
      pb.u = *(const uint4*)(WT + (size_t)(cf*16 + lc)*128 + k0);
      #pragma unroll
      for (int rf=0; rf<2; rf++)
        acc[rf][cf] = __builtin_amdgcn_mfma_f32_16x16x32_bf16(a[rf], pb.s, acc[rf][cf], 0, 0, 0);
    }
  }

  #pragma unroll
  for (int rf=0; rf<2; rf++){
    #pragma unroll
    for (int j=0; j<4; j++){
      int row = row0 + rf*16 + lg*4 + j;
      bool ok = (row < N);
      size_t nidx = (size_t)r*N + row;
      #pragma unroll
      for (int cf=0; cf<8; cf++){
        float v = acc[rf][cf][j];
        float pv = __shfl_xor(v, 1);
        if (ok && !(l&1))
          hq[nidx*64 + cf*8 + (lc>>1)] = bf16rn(v) | (bf16rn(pv)<<16);
      }
      float av = acc[rf][8][j];
      if (ok && lc < 4)       as_[nidx*4 + lc]     = av;
      else if (ok && lc < 8)  ad_[nidx*4 + (lc-4)] = av;
    }
  }
}

// --- CSR build: count per (rel,dst) ---
__global__ void k_count(const int* __restrict__ et, const int* __restrict__ ei,
                        int* __restrict__ counts, int E, int N){
  int e = blockIdx.x*256 + threadIdx.x;
  if (e >= E) return;
  int ty = et[e];
  int d  = ei[E + e];
  atomicAdd(&counts[(size_t)ty*N + d], 1);
}

// --- 3-kernel exclusive scan over M = 3N elements ---
__global__ void k_scan1(const int* __restrict__ counts, int* __restrict__ offs,
                        int* __restrict__ aux, int M){
  __shared__ int s[256];
  int idx = blockIdx.x*256 + threadIdx.x;
  int v = (idx < M) ? counts[idx] : 0;
  s[threadIdx.x] = v; __syncthreads();
  int x = v;
  for (int off=1; off<256; off<<=1){
    int y = (threadIdx.x >= off) ? s[threadIdx.x-off] : 0;
    __syncthreads();
    x += y; s[threadIdx.x] = x;
    __syncthreads();
  }
  if (idx < M) offs[idx] = x - v;
  if (threadIdx.x == 255) aux[blockIdx.x] = x;
}
__global__ void k_scan2(int* __restrict__ aux, int* __restrict__ offs, int M, int NB){
  __shared__ int s[1024];
  int t = threadIdx.x;
  int v = (t < NB) ? aux[t] : 0;
  s[t] = v; __syncthreads();
  int x = v;
  for (int off=1; off<1024; off<<=1){
    int y = (t >= off) ? s[t-off] : 0;
    __syncthreads();
    x += y; s[t] = x;
    __syncthreads();
  }
  if (t < NB) aux[t] = x - v;
  if (t == NB-1) offs[M] = x;
}
__global__ void k_scan3(int* __restrict__ offs, const int* __restrict__ aux, int M){
  int idx = blockIdx.x*256 + threadIdx.x;
  if (idx < M) offs[idx] += aux[idx>>8];
}

// --- scatter edges into CSR order; precompute per-edge 4-head scores ---
__global__ void k_scatter(const int* __restrict__ et, const int* __restrict__ ei,
                          int* __restrict__ cursor, const float* __restrict__ as_,
                          const float* __restrict__ ad_, int* __restrict__ ssrc,
                          float4* __restrict__ sscore, int E, int N){
  int e = blockIdx.x*256 + threadIdx.x;
  if (e >= E) return;
  int ty = et[e];
  int s  = ei[e];
  int d  = ei[E+e];
  int pos = atomicAdd(&cursor[(size_t)ty*N + d], 1);
  ssrc[pos] = s;
  float4 a = ((const float4*)as_)[(size_t)ty*N + s];
  float4 b = ((const float4*)ad_)[(size_t)ty*N + d];
  float4 sc;
  sc.x = leaky(a.x+b.x); sc.y = leaky(a.y+b.y);
  sc.z = leaky(a.z+b.z); sc.w = leaky(a.w+b.w);
  sscore[pos] = sc;
}

// --- per-dst softmax + aggregation: one wave per dst, 8 edges in flight ---
__global__ __launch_bounds__(256) void k_segment(
    const int* __restrict__ offs, const int* __restrict__ ssrc,
    const float4* __restrict__ sscore, const unsigned* __restrict__ hq,
    const float* __restrict__ as_, const float* __restrict__ ad_,
    const float* __restrict__ bias, const float* __restrict__ smw,
    float* __restrict__ out, int N){
  const int wave = threadIdx.x >> 6;
  const int lane = threadIdx.x & 63;
  const int dst  = blockIdx.x*4 + wave;
  if (dst >= N) return;
  const int g  = lane >> 3;   // edge group 0..7
  const int l8 = lane & 7;    // channel slot in group
  const int h0 = l8 >> 2;     // head of low 64-ch half (0/1); high half head = h0+2

  float sw[NREL];
  sw[0] = smw[0]; sw[1] = smw[1]; sw[2] = smw[2];

  float acc0[8], acc1[8];
  #pragma unroll
  for (int q=0; q<8; q++){ acc0[q]=0.f; acc1[q]=0.f; }

  #pragma unroll
  for (int r=0; r<NREL; r++){
    const size_t seg = (size_t)r*N + dst;
    int beg = __builtin_amdgcn_readfirstlane(offs[seg]);
    int end = __builtin_amdgcn_readfirstlane(offs[seg+1]);
    int len = end - beg;

    float4 a = ((const float4*)as_)[seg];
    float4 b = ((const float4*)ad_)[seg];
    float4 ssv;
    ssv.x = leaky(a.x+b.x); ssv.y = leaky(a.y+b.y);
    ssv.z = leaky(a.z+b.z); ssv.w = leaky(a.w+b.w);

    float4 m = ssv;
    float4 den = {0.f,0.f,0.f,0.f};
    if (len <= 16){
      // single load trip; butterfly within 16-lane groups (all 4 groups redundant)
      float4 sc = ssv;
      bool act = (lane & 15) < len;
      if (act){
        sc = sscore[beg + (lane & 15)];
        m.x=fmaxf(m.x,sc.x); m.y=fmaxf(m.y,sc.y);
        m.z=fmaxf(m.z,sc.z); m.w=fmaxf(m.w,sc.w);
      }
      #pragma unroll
      for (int o=8;o>0;o>>=1){
        m.x=fmaxf(m.x,__shfl_xor(m.x,o)); m.y=fmaxf(m.y,__shfl_xor(m.y,o));
        m.z=fmaxf(m.z,__shfl_xor(m.z,o)); m.w=fmaxf(m.w,__shfl_xor(m.w,o));
      }
      if (act){
        den.x=__expf(sc.x-m.x); den.y=__expf(sc.y-m.y);
        den.z=__expf(sc.z-m.z); den.w=__expf(sc.w-m.w);
      }
      #pragma unroll
      for (int o=8;o>0;o>>=1){
        den.x+=__shfl_xor(den.x,o); den.y+=__shfl_xor(den.y,o);
        den.z+=__shfl_xor(den.z,o); den.w+=__shfl_xor(den.w,o);
      }
    } else {
      for (int i=beg+lane; i<end; i+=64){
        float4 sc = sscore[i];
        m.x=fmaxf(m.x,sc.x); m.y=fmaxf(m.y,sc.y);
        m.z=fmaxf(m.z,sc.z); m.w=fmaxf(m.w,sc.w);
      }
      #pragma unroll
      for (int o=32;o>0;o>>=1){
        m.x=fmaxf(m.x,__shfl_xor(m.x,o)); m.y=fmaxf(m.y,__shfl_xor(m.y,o));
        m.z=fmaxf(m.z,__shfl_xor(m.z,o)); m.w=fmaxf(m.w,__shfl_xor(m.w,o));
      }
      for (int i=beg+lane; i<end; i+=64){
        float4 sc = sscore[i];
        den.x += __expf(sc.x-m.x); den.y += __expf(sc.y-m.y);
        den.z += __expf(sc.z-m.z); den.w += __expf(sc.w-m.w);
      }
      #pragma unroll
      for (int o=32;o>0;o>>=1){
        den.x+=__shfl_xor(den.x,o); den.y+=__shfl_xor(den.y,o);
        den.z+=__shfl_xor(den.z,o); den.w+=__shfl_xor(den.w,o);
      }
    }
    den.x += __expf(ssv.x-m.x); den.y += __expf(ssv.y-m.y);
    den.z += __expf(ssv.z-m.z); den.w += __expf(ssv.w-m.w);

    const float w = sw[r];
    const float m0 = (h0==0) ? m.x : m.y;
    const float m1 = (h0==0) ? m.z : m.w;
    const float iv0 = w / ((h0==0) ? den.x : den.y);
    const float iv1 = w / ((h0==0) ? den.z : den.w);
    const float sv0 = (h0==0) ? ssv.x : ssv.y;
    const float sv1 = (h0==0) ? ssv.z : ssv.w;

    const unsigned* hb = hq + (size_t)r*N*64;
    // 8 edges in flight: group g handles edge beg + trip*8 + g
    for (int i0=beg; i0<end; i0+=8){
      int i = i0 + g;
      if (i < end){
        int s = ssrc[i];
        float4 sc = sscore[i];
        float a0 = __expf(((h0==0)?sc.x:sc.y) - m0) * iv0;
        float a1 = __expf(((h0==0)?sc.z:sc.w) - m1) * iv1;
        const uint4* hp = (const uint4*)(hb + (size_t)s*64 + l8*4);
        uint4 u0 = hp[0];
        uint4 u1 = hp[8];
        const unsigned* p0 = (const unsigned*)&u0;
        const unsigned* p1 = (const unsigned*)&u1;
        #pragma unroll
        for (int q=0; q<4; q++){
          acc0[2*q]   = fmaf(a0, __uint_as_float(p0[q]<<16),           acc0[2*q]);
          acc0[2*q+1] = fmaf(a0, __uint_as_float(p0[q] & 0xFFFF0000u), acc0[2*q+1]);
          acc1[2*q]   = fmaf(a1, __uint_as_float(p1[q]<<16),           acc1[2*q]);
          acc1[2*q+1] = fmaf(a1, __uint_as_float(p1[q] & 0xFFFF0000u), acc1[2*q+1]);
        }
      }
    }
    // self-loop message (group 0 only)
    if (g == 0){
      float a0 = __expf(sv0 - m0) * iv0;
      float a1 = __expf(sv1 - m1) * iv1;
      const uint4* hp = (const uint4*)(hb + (size_t)dst*64 + l8*4);
      uint4 u0 = hp[0];
      uint4 u1 = hp[8];
      const unsigned* p0 = (const unsigned*)&u0;
      const unsigned* p1 = (const unsigned*)&u1;
      #pragma unroll
      for (int q=0; q<4; q++){
        acc0[2*q]   = fmaf(a0, __uint_as_float(p0[q]<<16),           acc0[2*q]);
        acc0[2*q+1] = fmaf(a0, __uint_as_float(p0[q] & 0xFFFF0000u), acc0[2*q+1]);
        acc1[2*q]   = fmaf(a1, __uint_as_float(p1[q]<<16),           acc1[2*q]);
        acc1[2*q+1] = fmaf(a1, __uint_as_float(p1[q] & 0xFFFF0000u), acc1[2*q+1]);
      }
    }
  }

  // cross-group reduction (xor 8,16,32)
  #pragma unroll
  for (int o=8; o<=32; o<<=1){
    #pragma unroll
    for (int q=0; q<8; q++){
      acc0[q] += __shfl_xor(acc0[q], o);
      acc1[q] += __shfl_xor(acc1[q], o);
    }
  }

  if (g == 0){
    // bias mix: sum_r sw[r]*bias[r][ch]
    float b0[8], b1[8];
    #pragma unroll
    for (int q=0; q<8; q++){ b0[q]=0.f; b1[q]=0.f; }
    #pragma unroll
    for (int r=0; r<NREL; r++){
      const float* bp = bias + (size_t)r*OUT_DIM;
      float4 x0 = *(const float4*)(bp + 8*l8);
      float4 x1 = *(const float4*)(bp + 8*l8 + 4);
      float4 y0 = *(const float4*)(bp + 64 + 8*l8);
      float4 y1 = *(const float4*)(bp + 64 + 8*l8 + 4);
      float w = sw[r];
      b0[0]=fmaf(w,x0.x,b0[0]); b0[1]=fmaf(w,x0.y,b0[1]); b0[2]=fmaf(w,x0.z,b0[2]); b0[3]=fmaf(w,x0.w,b0[3]);
      b0[4]=fmaf(w,x1.x,b0[4]); b0[5]=fmaf(w,x1.y,b0[5]); b0[6]=fmaf(w,x1.z,b0[6]); b0[7]=fmaf(w,x1.w,b0[7]);
      b1[0]=fmaf(w,y0.x,b1[0]); b1[1]=fmaf(w,y0.y,b1[1]); b1[2]=fmaf(w,y0.z,b1[2]); b1[3]=fmaf(w,y0.w,b1[3]);
      b1[4]=fmaf(w,y1.x,b1[4]); b1[5]=fmaf(w,y1.y,b1[5]); b1[6]=fmaf(w,y1.z,b1[6]); b1[7]=fmaf(w,y1.w,b1[7]);
    }
    float* orow = out + (size_t)dst*128;
    float4 o0 = {acc0[0]+b0[0], acc0[1]+b0[1], acc0[2]+b0[2], acc0[3]+b0[3]};
    float4 o1 = {acc0[4]+b0[4], acc0[5]+b0[5], acc0[6]+b0[6], acc0[7]+b0[7]};
    float4 o2 = {acc1[0]+b1[0], acc1[1]+b1[1], acc1[2]+b1[2], acc1[3]+b1[3]};
    float4 o3 = {acc1[4]+b1[4], acc1[5]+b1[5], acc1[6]+b1[6], acc1[7]+b1[7]};
    *(float4*)(orow + 8*l8)          = o0;
    *(float4*)(orow + 8*l8 + 4)      = o1;
    *(float4*)(orow + 64 + 8*l8)     = o2;
    *(float4*)(orow + 64 + 8*l8 + 4) = o3;
  }
}

extern "C" void kernel_launch(void* const* d_in, const int* in_sizes, int n_in,
                              void* d_out, int out_size, void* d_ws, size_t ws_size,
                              hipStream_t stream) {
  const float* x     = (const float*)d_in[0];
  const float* W     = (const float*)d_in[1];
  const float* att_s = (const float*)d_in[2];
  const float* att_d = (const float*)d_in[3];
  const float* bias  = (const float*)d_in[4];
  const float* rw    = (const float*)d_in[5];
  const int*   ei    = (const int*)d_in[6];
  const int*   et    = (const int*)d_in[7];
  float* out = (float*)d_out;

  const int N = in_sizes[0] / IN_DIM;
  const int E = in_sizes[7];
  const int M = NREL * N;

  char* ws = (char*)d_ws;
  size_t off = 0;
  auto alloc = [&](size_t bytes) -> void* {
    void* p = ws + off; off += (bytes + 255) & ~(size_t)255; return p;
  };
  unsigned* hq     = (unsigned*)alloc((size_t)M * 64 * 4);
  float*    as_    = (float*)   alloc((size_t)M * 4 * 4);
  float*    ad_    = (float*)   alloc((size_t)M * 4 * 4);
  int*      counts = (int*)     alloc((size_t)M * 4);
  int*      offs   = (int*)     alloc(((size_t)M + 1) * 4);
  int*      cursor = (int*)     alloc((size_t)M * 4);
  int*      aux    = (int*)     alloc(4096);
  int*      ssrc   = (int*)     alloc((size_t)E * 4);
  float4*   sscore = (float4*)  alloc((size_t)E * 16);
  float*    smw    = (float*)   alloc(256);
  u16*      WTall  = (u16*)     alloc((size_t)NREL * 144 * 128 * 2);

  hipMemsetAsync(counts, 0, (size_t)M * 4, stream);
  k_prep<<<1, 64, 0, stream>>>(rw, smw);
  k_wprep<<<NREL, 256, 0, stream>>>(W, att_s, att_d, WTall);
  dim3 g1((N + 127) / 128, NREL);
  k_gemm<<<g1, 256, 0, stream>>>(x, WTall, hq, as_, ad_, N);
  k_count<<<(E + 255) / 256, 256, 0, stream>>>(et, ei, counts, E, N);
  const int NB = (M + 255) / 256;
  k_scan1<<<NB, 256, 0, stream>>>(counts, offs, aux, M);
  k_scan2<<<1, 1024, 0, stream>>>(aux, offs, M, NB);
  k_scan3<<<NB, 256, 0, stream>>>(offs, aux, M);
  hipMemcpyAsync(cursor, offs, (size_t)M * 4, hipMemcpyDeviceToDevice, stream);
  k_scatter<<<(E + 255) / 256, 256, 0, stream>>>(et, ei, cursor, as_, ad_, ssrc, sscore, E, N);
  k_segment<<<(N + 3) / 4, 256, 0, stream>>>(offs, ssrc, sscore, hq, as_, ad_, bias, smw, out, N);
}